// Round 9
// baseline (3172.458 us; speedup 1.0000x reference)
//
#include <hip/hip_runtime.h>
#include <math.h>

// Problem constants (match reference)
#define Hn   2560      // hidden units
#define Bn   64        // batch
#define INW  128       // input width
#define ETOT 2048      // total excitatory units (4 areas x 512)
#define HGn  160       // h-groups of 16
#define MAXC 13        // max 128-k chunks per h-group
#define NBLK 160       // grid size == HGn (co-resident: 160 <= 256 CUs @ 1 blk/CU)
#define MAXI 7         // max k-steps per wave: ceil(52/8)

typedef __attribute__((ext_vector_type(8))) _Float16 half8;  // 8 f16 = 4 VGPRs
typedef __attribute__((ext_vector_type(4))) float  floatx4;  // MFMA acc / NT store

// ---------------------------------------------------------------------------
// Prep: masked signed W -> MFMA A-fragments, split hi/lo f16 (W to 2^-22 rel).
// Af[(hg*13+c)] = 4 kq x {hi,lo} x 64 lanes x 8 f16 (8 KB per 128-k chunk).
// A[m][k]: m = lane&15, k = (lane>>4)*8 + j.   (unchanged)
// ---------------------------------------------------------------------------
__global__ void build_apack(const float* __restrict__ Wrec,
                            const float* __restrict__ Win,
                            _Float16* __restrict__ Af) {
  int hg = blockIdx.x, c = blockIdx.y;
  int a = (hg < 128) ? (hg >> 5) : ((hg - 128) >> 3);
  int nE = (a == 0 || a == 3) ? 8 : 12;
  int nch = nE + 1 + (a == 0 ? 1 : 0);
  if (c >= nch) return;
  int h0 = hg * 16;
  int tid = threadIdx.x;
  int kq = tid >> 6, L = tid & 63;
  int m = L & 15, q = L >> 4;
  int h = h0 + m;

  const float* src; int k0, stride; float sgn; bool isIn = false;
  if (c < nE)       { k0 = ((a == 0 ? 0 : a - 1) << 9) + (c << 7); src = Wrec; stride = Hn;  sgn =  1.f; }
  else if (c == nE) { k0 = ETOT + (a << 7);                        src = Wrec; stride = Hn;  sgn = -1.f; }
  else              { k0 = 0;                                      src = Win;  stride = INW; sgn =  1.f; isIn = true; }

  _Float16 hi8[8], lo8[8];
  #pragma unroll
  for (int j = 0; j < 8; ++j) {
    int k = k0 + kq * 32 + q * 8 + j;
    float w = fabsf(src[(size_t)h * stride + k]);
    if (!isIn && k == h) w = 0.f;     // remove_diag
    w *= sgn;
    _Float16 wh = (_Float16)w;
    hi8[j] = wh;
    lo8[j] = (_Float16)(w - (float)wh);
  }
  _Float16* outp = Af + (size_t)(hg * MAXC + c) * 4096;
  *(uint4*)(outp + (kq * 2 + 0) * 512 + L * 8) = *(const uint4*)hi8;
  *(uint4*)(outp + (kq * 2 + 1) * 512 + L * 8) = *(const uint4*)lo8;
}

// ---- LLC-coherent (sc0 sc1: performed at MALL, bypass L1/L2) rf access ----
// waitcnt lives INSIDE each asm block with its loads => no hoisting hazard,
// no pending counters across asm boundaries (R5's AGPR-shuttle failure).
#define LOADQ(Q0,Q1,Q2,Q3,R0,R1,R2,R3,S0,S1,S2,S3,U0,U1,U2,U3,P0,P1,P2,P3) \
  asm volatile("global_load_dwordx4 %0, %16, off sc0 sc1\n\t" \
               "global_load_dwordx4 %1, %16, off offset:1024 sc0 sc1\n\t" \
               "global_load_dwordx4 %2, %16, off offset:2048 sc0 sc1\n\t" \
               "global_load_dwordx4 %3, %16, off offset:3072 sc0 sc1\n\t" \
               "global_load_dwordx4 %4, %17, off sc0 sc1\n\t" \
               "global_load_dwordx4 %5, %17, off offset:1024 sc0 sc1\n\t" \
               "global_load_dwordx4 %6, %17, off offset:2048 sc0 sc1\n\t" \
               "global_load_dwordx4 %7, %17, off offset:3072 sc0 sc1\n\t" \
               "global_load_dwordx4 %8, %18, off sc0 sc1\n\t" \
               "global_load_dwordx4 %9, %18, off offset:1024 sc0 sc1\n\t" \
               "global_load_dwordx4 %10, %18, off offset:2048 sc0 sc1\n\t" \
               "global_load_dwordx4 %11, %18, off offset:3072 sc0 sc1\n\t" \
               "global_load_dwordx4 %12, %19, off sc0 sc1\n\t" \
               "global_load_dwordx4 %13, %19, off offset:1024 sc0 sc1\n\t" \
               "global_load_dwordx4 %14, %19, off offset:2048 sc0 sc1\n\t" \
               "global_load_dwordx4 %15, %19, off offset:3072 sc0 sc1\n\t" \
               "s_waitcnt vmcnt(0)" \
               : "=&v"(Q0), "=&v"(Q1), "=&v"(Q2), "=&v"(Q3), \
                 "=&v"(R0), "=&v"(R1), "=&v"(R2), "=&v"(R3), \
                 "=&v"(S0), "=&v"(S1), "=&v"(S2), "=&v"(S3), \
                 "=&v"(U0), "=&v"(U1), "=&v"(U2), "=&v"(U3) \
               : "v"(P0), "v"(P1), "v"(P2), "v"(P3) : "memory")

#define LOADT(Q0,Q1,Q2,Q3,R0,R1,R2,R3,S0,S1,S2,S3,P0,P1,P2) \
  asm volatile("global_load_dwordx4 %0, %12, off sc0 sc1\n\t" \
               "global_load_dwordx4 %1, %12, off offset:1024 sc0 sc1\n\t" \
               "global_load_dwordx4 %2, %12, off offset:2048 sc0 sc1\n\t" \
               "global_load_dwordx4 %3, %12, off offset:3072 sc0 sc1\n\t" \
               "global_load_dwordx4 %4, %13, off sc0 sc1\n\t" \
               "global_load_dwordx4 %5, %13, off offset:1024 sc0 sc1\n\t" \
               "global_load_dwordx4 %6, %13, off offset:2048 sc0 sc1\n\t" \
               "global_load_dwordx4 %7, %13, off offset:3072 sc0 sc1\n\t" \
               "global_load_dwordx4 %8, %14, off sc0 sc1\n\t" \
               "global_load_dwordx4 %9, %14, off offset:1024 sc0 sc1\n\t" \
               "global_load_dwordx4 %10, %14, off offset:2048 sc0 sc1\n\t" \
               "global_load_dwordx4 %11, %14, off offset:3072 sc0 sc1\n\t" \
               "s_waitcnt vmcnt(0)" \
               : "=&v"(Q0), "=&v"(Q1), "=&v"(Q2), "=&v"(Q3), \
                 "=&v"(R0), "=&v"(R1), "=&v"(R2), "=&v"(R3), \
                 "=&v"(S0), "=&v"(S1), "=&v"(S2), "=&v"(S3) \
               : "v"(P0), "v"(P1), "v"(P2) : "memory")

#define LOAD8(X0,X1,X2,X3,Y0,Y1,Y2,Y3,PA,PB) \
  asm volatile("global_load_dwordx4 %0, %8, off sc0 sc1\n\t" \
               "global_load_dwordx4 %1, %8, off offset:1024 sc0 sc1\n\t" \
               "global_load_dwordx4 %2, %8, off offset:2048 sc0 sc1\n\t" \
               "global_load_dwordx4 %3, %8, off offset:3072 sc0 sc1\n\t" \
               "global_load_dwordx4 %4, %9, off sc0 sc1\n\t" \
               "global_load_dwordx4 %5, %9, off offset:1024 sc0 sc1\n\t" \
               "global_load_dwordx4 %6, %9, off offset:2048 sc0 sc1\n\t" \
               "global_load_dwordx4 %7, %9, off offset:3072 sc0 sc1\n\t" \
               "s_waitcnt vmcnt(0)" \
               : "=&v"(X0), "=&v"(X1), "=&v"(X2), "=&v"(X3), \
                 "=&v"(Y0), "=&v"(Y1), "=&v"(Y2), "=&v"(Y3) \
               : "v"(PA), "v"(PB) : "memory")

#define LOAD4(B0,B1,B2,B3,P) \
  asm volatile("global_load_dwordx4 %0, %4, off sc0 sc1\n\t" \
               "global_load_dwordx4 %1, %4, off offset:1024 sc0 sc1\n\t" \
               "global_load_dwordx4 %2, %4, off offset:2048 sc0 sc1\n\t" \
               "global_load_dwordx4 %3, %4, off offset:3072 sc0 sc1\n\t" \
               "s_waitcnt vmcnt(0)" \
               : "=&v"(B0), "=&v"(B1), "=&v"(B2), "=&v"(B3) \
               : "v"(P) : "memory")

#define MFMA8(i, B0,B1,B2,B3) do { \
  ac0 = __builtin_amdgcn_mfma_f32_16x16x32_f16(ah[i], B0, ac0, 0, 0, 0); \
  ac0 = __builtin_amdgcn_mfma_f32_16x16x32_f16(al[i], B0, ac0, 0, 0, 0); \
  ac1 = __builtin_amdgcn_mfma_f32_16x16x32_f16(ah[i], B1, ac1, 0, 0, 0); \
  ac1 = __builtin_amdgcn_mfma_f32_16x16x32_f16(al[i], B1, ac1, 0, 0, 0); \
  ac2 = __builtin_amdgcn_mfma_f32_16x16x32_f16(ah[i], B2, ac2, 0, 0, 0); \
  ac2 = __builtin_amdgcn_mfma_f32_16x16x32_f16(al[i], B2, ac2, 0, 0, 0); \
  ac3 = __builtin_amdgcn_mfma_f32_16x16x32_f16(ah[i], B3, ac3, 0, 0, 0); \
  ac3 = __builtin_amdgcn_mfma_f32_16x16x32_f16(al[i], B3, ac3, 0, 0, 0); \
} while (0)

// ---------------------------------------------------------------------------
// Persistent kernel — R8 base (2796us proven: sc0sc1 LLC exchange,
// hierarchical 8x20->master->replicated-gen barrier, fast retanh, tail
// reorder, NO cache maintenance in loop) + ONE change:
//  - QUAD+remainder load batching: load phase 4 RTs -> 2 RTs. R7 bundled
//    this with the flat barrier (condemned by R8's A/B); retrying clean.
//    launch_bounds(512,1) gives the allocator a 256-VGPR budget so the
//    64 B-frag + 56 A-frag live set fits without AGPR shuttling (160 blks
//    on 256 CUs -> 1 blk/CU either way; occupancy unchanged).
// ---------------------------------------------------------------------------
__global__ __launch_bounds__(512, 1) void rnn_persist(
    const _Float16* __restrict__ Af,
    const float* __restrict__ inputs,
    _Float16* __restrict__ rfA, _Float16* __restrict__ rfB,
    const float* __restrict__ brec,
    float* __restrict__ rates,
    unsigned* bar, int T)
{
  __shared__ float red[8][1056];     // 8 wave-partials, 16 x 66-padded
  __shared__ float rrt[16][68];      // rates staging (padded)
  __shared__ float bb[16];

  const int hg  = blockIdx.x;
  const int tid = threadIdx.x;
  const int w   = tid >> 6, L = tid & 63;
  const int h0  = hg * 16;
  const int a   = (hg < 128) ? (hg >> 5) : ((hg - 128) >> 3);
  const int nE  = (a == 0 || a == 3) ? 8 : 12;
  const int SK  = (nE + 1 + (a == 0 ? 1 : 0)) * 4;   // 40 / 52 / 52 / 36
  const int ktE0 = (a == 0 ? 0 : a - 1) * 16;
  const int ktI0 = 64 + a * 4;

  unsigned* bsub = bar + (hg & 7) * 64;        // 8 sub-counters (20 blocks ea)
  unsigned* bmas = bar + 8 * 64;               // master (+1 per sub-group)
  unsigned* bgen = bar + (9 + (hg & 7)) * 64;  // replicated release flag

  if (tid < 16) bb[tid] = brec[h0 + tid];

  // ---- one-time A preload + pin in VGPRs ----
  half8 ah[MAXI], al[MAXI];
  int   boff[MAXI];
  bool  act[MAXI], isin[MAXI];
  const _Float16* Abase = Af + (size_t)hg * MAXC * 4096;
  #pragma unroll
  for (int i = 0; i < MAXI; ++i) {
    half8 zz = {0,0,0,0,0,0,0,0};
    ah[i] = zz; al[i] = zz;
    int ks = w + i * 8;
    act[i]  = ks < SK;
    isin[i] = false;
    boff[i] = 0;
    if (act[i]) {
      int c = ks >> 2, kq = ks & 3;
      const _Float16* Ap = Abase + (size_t)c * 4096 + (size_t)(kq * 2) * 512 + (size_t)L * 8;
      ah[i] = *(const half8*)Ap;
      al[i] = *(const half8*)(Ap + 512);
      if (c <= nE) {           // recurrent chunk: rf offset (half units)
        int kt = (c < nE) ? (ktE0 + c * 4 + kq) : (ktI0 + kq);
        boff[i] = kt * 2048 + L * 8;
      } else {                 // input chunk (area 0): inputs offset base
        isin[i] = true;
        boff[i] = kq * 32 + (L >> 4) * 8;
      }
    }
  }
  // opaque pin: values now "produced" by asm -> cannot be rematerialized
  #pragma unroll
  for (int i = 0; i < MAXI; ++i)
    asm volatile("" : "+v"(ah[i]), "+v"(al[i]));

  // Rn = leading rec-chunk count (act prefix-true, isin only last): 4..7.
  int Rn = 0;
  while (Rn < MAXI && act[Rn] && !isin[Rn]) ++Rn;
  const bool hasIn = (Rn < MAXI) && act[Rn] && isin[Rn];
  const int  rem   = Rn - 4;                         // 0..3

  float xv[2] = {0.f, 0.f};    // x state: 2 elems/thread, lives in regs

  __syncthreads();             // bb ready

  for (int t = 0; t < T; ++t) {
    const _Float16* __restrict__ rs = (t & 1) ? rfB : rfA;
    _Float16* __restrict__ rd       = (t & 1) ? rfA : rfB;

    floatx4 ac0 = {0.f,0.f,0.f,0.f}, ac1 = {0.f,0.f,0.f,0.f};
    floatx4 ac2 = {0.f,0.f,0.f,0.f}, ac3 = {0.f,0.f,0.f,0.f};

    // -- input chunk first (compiler-managed loads, consumed before any asm
    //    loads are pending -> waitcnt models never mix) --
    if (hasIn) {
      const float* ip = inputs + (size_t)t * (Bn * INW) + boff[Rn];
      int nb = L & 15;
      half8 b0, b1, b2, b3;
      #pragma unroll
      for (int j = 0; j < 8; ++j) b0[j] = (_Float16)ip[(nb +  0) * INW + j];
      #pragma unroll
      for (int j = 0; j < 8; ++j) b1[j] = (_Float16)ip[(nb + 16) * INW + j];
      #pragma unroll
      for (int j = 0; j < 8; ++j) b2[j] = (_Float16)ip[(nb + 32) * INW + j];
      #pragma unroll
      for (int j = 0; j < 8; ++j) b3[j] = (_Float16)ip[(nb + 48) * INW + j];
      MFMA8(Rn, b0, b1, b2, b3);
    }

    // -- QUAD: chunks 0..3, one MALL round trip --
    {
      half8 q0,q1,q2,q3, r0,r1,r2,r3, s0,s1,s2,s3, u0,u1,u2,u3;
      const _Float16* p0 = rs + boff[0];
      const _Float16* p1 = rs + boff[1];
      const _Float16* p2 = rs + boff[2];
      const _Float16* p3 = rs + boff[3];
      LOADQ(q0,q1,q2,q3, r0,r1,r2,r3, s0,s1,s2,s3, u0,u1,u2,u3, p0,p1,p2,p3);
      MFMA8(0, q0,q1,q2,q3);
      MFMA8(1, r0,r1,r2,r3);
      MFMA8(2, s0,s1,s2,s3);
      MFMA8(3, u0,u1,u2,u3);
    }
    // -- remainder: chunks 4..Rn-1, one round trip (wave-uniform branch) --
    if (rem == 3) {
      half8 q0,q1,q2,q3, r0,r1,r2,r3, s0,s1,s2,s3;
      const _Float16* p0 = rs + boff[4];
      const _Float16* p1 = rs + boff[5];
      const _Float16* p2 = rs + boff[6];
      LOADT(q0,q1,q2,q3, r0,r1,r2,r3, s0,s1,s2,s3, p0,p1,p2);
      MFMA8(4, q0,q1,q2,q3);
      MFMA8(5, r0,r1,r2,r3);
      MFMA8(6, s0,s1,s2,s3);
    } else if (rem == 2) {
      half8 q0,q1,q2,q3, r0,r1,r2,r3;
      const _Float16* p0 = rs + boff[4];
      const _Float16* p1 = rs + boff[5];
      LOAD8(q0,q1,q2,q3, r0,r1,r2,r3, p0,p1);
      MFMA8(4, q0,q1,q2,q3);
      MFMA8(5, r0,r1,r2,r3);
    } else if (rem == 1) {
      half8 q0,q1,q2,q3;
      const _Float16* p0 = rs + boff[4];
      LOAD4(q0,q1,q2,q3, p0);
      MFMA8(4, q0,q1,q2,q3);
    }

    // dump split-k partials to LDS
    #pragma unroll
    for (int p = 0; p < 4; ++p) {
      int m = (L >> 4) * 4 + p;
      float* rw = &red[w][m * 66 + (L & 15)];
      rw[ 0] = ac0[p];
      rw[16] = ac1[p];
      rw[32] = ac2[p];
      rw[48] = ac3[p];
    }
    __syncthreads();

    // reduce 8 partials + bias + leaky-integrate + fast retanh
    #pragma unroll
    for (int e = 0; e < 2; ++e) {
      int elem = tid + e * 512;
      int m = elem >> 6, n = elem & 63;
      float s = 0.f;
      #pragma unroll
      for (int j = 0; j < 8; ++j) s += red[j][m * 66 + n];
      float x = 0.8f * xv[e] + 0.2f * (s + bb[m]);   // ALPHA_X = 0.2
      xv[e] = x;
      // retanh(x) = tanh(max(x,0)) = 1 - 2/(exp2(2x*log2e)+1) (R7/R8-proven)
      float xr = fmaxf(x, 0.f);
      float e2 = __builtin_amdgcn_exp2f(xr * 2.885390081777926814f);
      rrt[m][n] = 1.0f - 2.0f * __builtin_amdgcn_rcpf(e2 + 1.0f);
    }
    __syncthreads();

    // tid<128: emit next-step r B-fragments via MALL-coherent stores.
    // vmcnt(0) inside the asm: data at the LLC before barrier arrival.
    if (tid < 128) {
      int bt = tid >> 5, Lq = tid & 31;
      int Lp = (hg & 1) * 32 + Lq;
      half8 vv;
      #pragma unroll
      for (int j = 0; j < 8; ++j)
        vv[j] = (_Float16)rrt[(Lq >> 4) * 8 + j][bt * 16 + (Lq & 15)];
      _Float16* dst = rd + (size_t)((hg >> 1) * 4 + bt) * 512 + (size_t)Lp * 8;
      asm volatile("global_store_dwordx4 %0, %1, off sc0 sc1\n\t"
                   "s_waitcnt vmcnt(0)"
                   :: "v"(dst), "v"(vv) : "memory");
    }
    __syncthreads();   // all waves' rf stores complete (asm-internal vmcnt 0)

    // ---- arrive (hierarchical, R4/R8-proven), BEFORE the rates store ----
    unsigned g = (unsigned)(t + 1);
    if (t + 1 < T && tid == 0) {
      unsigned s = __hip_atomic_fetch_add(bsub, 1u, __ATOMIC_RELAXED,
                                          __HIP_MEMORY_SCOPE_AGENT);
      if (s == g * 20u - 1u) {
        unsigned m2 = __hip_atomic_fetch_add(bmas, 1u, __ATOMIC_RELAXED,
                                             __HIP_MEMORY_SCOPE_AGENT);
        if (m2 == g * 8u - 1u) {
          #pragma unroll
          for (int x = 0; x < 8; ++x)
            __hip_atomic_store(bar + (9 + x) * 64, g, __ATOMIC_RELAXED,
                               __HIP_MEMORY_SCOPE_AGENT);
        }
      }
    }

    // rates store overlaps the poll below (HBM drain off the critical path)
    if (tid >= 256) {
      int tt = tid - 256;
      int b = tt >> 2, hq = tt & 3;
      floatx4 o;
      o.x = rrt[hq * 4 + 0][b];
      o.y = rrt[hq * 4 + 1][b];
      o.z = rrt[hq * 4 + 2][b];
      o.w = rrt[hq * 4 + 3][b];
      __builtin_nontemporal_store(o,
          (floatx4*)(rates + (size_t)t * (Bn * Hn) + (size_t)b * Hn + h0 + hq * 4));
    }

    if (t + 1 < T) {
      if (tid == 0) {
        while (__hip_atomic_load(bgen, __ATOMIC_RELAXED,
                                 __HIP_MEMORY_SCOPE_AGENT) < g)
          __builtin_amdgcn_s_sleep(2);
      }
      __syncthreads();   // block released; next rf reads are sc0sc1 (fresh)
    }
  }
}

// ---------------------------------------------------------------------------
extern "C" void kernel_launch(void* const* d_in, const int* in_sizes, int n_in,
                              void* d_out, int out_size, void* d_ws, size_t ws_size,
                              hipStream_t stream) {
  const float* inputs = (const float*)d_in[0];   // [T, 64, 128]
  const float* Wrec   = (const float*)d_in[1];   // [2560, 2560]
  const float* brec   = (const float*)d_in[2];   // [2560]
  const float* Win    = (const float*)d_in[3];   // [2560, 128]
  int T = in_sizes[0] / (Bn * INW);              // 500

  char* base = (char*)d_ws;
  size_t off = 0;
  _Float16* Af  = (_Float16*)(base + off); off += (size_t)HGn * MAXC * 4096 * 2;  // 17.0 MB
  _Float16* rfA = (_Float16*)(base + off); off += (size_t)80 * 4 * 512 * 2;       // 320 KB
  _Float16* rfB = (_Float16*)(base + off); off += (size_t)80 * 4 * 512 * 2;       // 320 KB
  unsigned* bar = (unsigned*)(base + off); off += 8192;                           // barrier state (17 lines)

  // r0 = retanh(0) = 0 (f16 zero == 0x0000); ws poisoned each call, so rfA
  // and the barrier counters must be re-zeroed every launch.
  (void)hipMemsetAsync(rfA, 0, (size_t)80 * 4 * 512 * 2, stream);
  (void)hipMemsetAsync(bar, 0, 8192, stream);

  build_apack<<<dim3(HGn, MAXC), 256, 0, stream>>>(Wrec, Win, Af);

  float* rates = (float*)d_out;
  rnn_persist<<<NBLK, 512, 0, stream>>>(Af, inputs, rfA, rfB, brec, rates,
                                        bar, T);
}

// Round 10
// 2701.263 us; speedup vs baseline: 1.1744x; 1.1744x over previous
//
#include <hip/hip_runtime.h>
#include <math.h>

// Problem constants (match reference)
#define Hn   2560      // hidden units
#define Bn   64        // batch
#define INW  128       // input width
#define ETOT 2048      // total excitatory units (4 areas x 512)
#define HGn  160       // h-groups of 16
#define MAXC 13        // max 128-k chunks per h-group
#define NBLK 160       // grid size == HGn (co-resident: 160 <= 256 CUs @ 1 blk/CU)
#define MAXI 7         // max k-steps per wave: ceil(52/8)
#define RFSTRIDE (80 * 4 * 512)   // one rf slot, in _Float16 units (320 KB)

typedef __attribute__((ext_vector_type(8))) _Float16 half8;  // 8 f16 = 4 VGPRs
typedef __attribute__((ext_vector_type(4))) float  floatx4;  // MFMA acc / NT store

// ---------------------------------------------------------------------------
// Prep: masked signed W -> MFMA A-fragments, split hi/lo f16 (unchanged)
// ---------------------------------------------------------------------------
__global__ void build_apack(const float* __restrict__ Wrec,
                            const float* __restrict__ Win,
                            _Float16* __restrict__ Af) {
  int hg = blockIdx.x, c = blockIdx.y;
  int a = (hg < 128) ? (hg >> 5) : ((hg - 128) >> 3);
  int nE = (a == 0 || a == 3) ? 8 : 12;
  int nch = nE + 1 + (a == 0 ? 1 : 0);
  if (c >= nch) return;
  int h0 = hg * 16;
  int tid = threadIdx.x;
  int kq = tid >> 6, L = tid & 63;
  int m = L & 15, q = L >> 4;
  int h = h0 + m;

  const float* src; int k0, stride; float sgn; bool isIn = false;
  if (c < nE)       { k0 = ((a == 0 ? 0 : a - 1) << 9) + (c << 7); src = Wrec; stride = Hn;  sgn =  1.f; }
  else if (c == nE) { k0 = ETOT + (a << 7);                        src = Wrec; stride = Hn;  sgn = -1.f; }
  else              { k0 = 0;                                      src = Win;  stride = INW; sgn =  1.f; isIn = true; }

  _Float16 hi8[8], lo8[8];
  #pragma unroll
  for (int j = 0; j < 8; ++j) {
    int k = k0 + kq * 32 + q * 8 + j;
    float w = fabsf(src[(size_t)h * stride + k]);
    if (!isIn && k == h) w = 0.f;     // remove_diag
    w *= sgn;
    _Float16 wh = (_Float16)w;
    hi8[j] = wh;
    lo8[j] = (_Float16)(w - (float)wh);
  }
  _Float16* outp = Af + (size_t)(hg * MAXC + c) * 4096;
  *(uint4*)(outp + (kq * 2 + 0) * 512 + L * 8) = *(const uint4*)hi8;
  *(uint4*)(outp + (kq * 2 + 1) * 512 + L * 8) = *(const uint4*)lo8;
}

// ---- LLC-coherent (sc0 sc1) rf loads, wait inside the asm (R4-proven) ----
#define LOAD4(B0,B1,B2,B3,P) \
  asm volatile("global_load_dwordx4 %0, %4, off sc0 sc1\n\t" \
               "global_load_dwordx4 %1, %4, off offset:1024 sc0 sc1\n\t" \
               "global_load_dwordx4 %2, %4, off offset:2048 sc0 sc1\n\t" \
               "global_load_dwordx4 %3, %4, off offset:3072 sc0 sc1\n\t" \
               "s_waitcnt vmcnt(0)" \
               : "=&v"(B0), "=&v"(B1), "=&v"(B2), "=&v"(B3) \
               : "v"(P) : "memory")

#define LOAD8(X0,X1,X2,X3,Y0,Y1,Y2,Y3,PA,PB) \
  asm volatile("global_load_dwordx4 %0, %8, off sc0 sc1\n\t" \
               "global_load_dwordx4 %1, %8, off offset:1024 sc0 sc1\n\t" \
               "global_load_dwordx4 %2, %8, off offset:2048 sc0 sc1\n\t" \
               "global_load_dwordx4 %3, %8, off offset:3072 sc0 sc1\n\t" \
               "global_load_dwordx4 %4, %9, off sc0 sc1\n\t" \
               "global_load_dwordx4 %5, %9, off offset:1024 sc0 sc1\n\t" \
               "global_load_dwordx4 %6, %9, off offset:2048 sc0 sc1\n\t" \
               "global_load_dwordx4 %7, %9, off offset:3072 sc0 sc1\n\t" \
               "s_waitcnt vmcnt(0)" \
               : "=&v"(X0), "=&v"(X1), "=&v"(X2), "=&v"(X3), \
                 "=&v"(Y0), "=&v"(Y1), "=&v"(Y2), "=&v"(Y3) \
               : "v"(PA), "v"(PB) : "memory")

#define MFMA8(i, B0,B1,B2,B3) do { \
  ac0 = __builtin_amdgcn_mfma_f32_16x16x32_f16(ah[i], B0, ac0, 0, 0, 0); \
  ac0 = __builtin_amdgcn_mfma_f32_16x16x32_f16(al[i], B0, ac0, 0, 0, 0); \
  ac1 = __builtin_amdgcn_mfma_f32_16x16x32_f16(ah[i], B1, ac1, 0, 0, 0); \
  ac1 = __builtin_amdgcn_mfma_f32_16x16x32_f16(al[i], B1, ac1, 0, 0, 0); \
  ac2 = __builtin_amdgcn_mfma_f32_16x16x32_f16(ah[i], B2, ac2, 0, 0, 0); \
  ac2 = __builtin_amdgcn_mfma_f32_16x16x32_f16(al[i], B2, ac2, 0, 0, 0); \
  ac3 = __builtin_amdgcn_mfma_f32_16x16x32_f16(ah[i], B3, ac3, 0, 0, 0); \
  ac3 = __builtin_amdgcn_mfma_f32_16x16x32_f16(al[i], B3, ac3, 0, 0, 0); \
} while (0)

#define RECPATH1(i) do { \
  half8 B0_, B1_, B2_, B3_; \
  const _Float16* pp_ = rs + boff[i]; \
  LOAD4(B0_, B1_, B2_, B3_, pp_); \
  MFMA8(i, B0_, B1_, B2_, B3_); \
} while (0)

#define INPATH(i) do { \
  const float* ip_ = inputs + (size_t)t * (Bn * INW) + boff[i]; \
  int nb_ = L & 15; \
  half8 B0_, B1_, B2_, B3_; \
  _Pragma("unroll") for (int j = 0; j < 8; ++j) B0_[j] = (_Float16)ip_[(nb_ +  0) * INW + j]; \
  _Pragma("unroll") for (int j = 0; j < 8; ++j) B1_[j] = (_Float16)ip_[(nb_ + 16) * INW + j]; \
  _Pragma("unroll") for (int j = 0; j < 8; ++j) B2_[j] = (_Float16)ip_[(nb_ + 32) * INW + j]; \
  _Pragma("unroll") for (int j = 0; j < 8; ++j) B3_[j] = (_Float16)ip_[(nb_ + 48) * INW + j]; \
  MFMA8(i, B0_, B1_, B2_, B3_); \
} while (0)

#define PAIR(i0, i1) do { \
  bool r0_ = act[i0] && !isin[i0]; \
  bool r1_ = act[i1] && !isin[i1]; \
  if (r0_ && r1_) { \
    half8 X0_,X1_,X2_,X3_,Y0_,Y1_,Y2_,Y3_; \
    const _Float16* pa_ = rs + boff[i0]; \
    const _Float16* pb_ = rs + boff[i1]; \
    LOAD8(X0_,X1_,X2_,X3_,Y0_,Y1_,Y2_,Y3_, pa_, pb_); \
    MFMA8(i0, X0_, X1_, X2_, X3_); \
    MFMA8(i1, Y0_, Y1_, Y2_, Y3_); \
  } else { \
    if (r0_) RECPATH1(i0); else if (act[i0]) INPATH(i0); \
    if (r1_) RECPATH1(i1); else if (act[i1]) INPATH(i1); \
  } \
} while (0)

// ---------------------------------------------------------------------------
// Persistent kernel, two variants:
//  ROT=1 (if workspace >= (T+1) rf slots): each step writes rf to a FRESH
//    slot via sc0sc1 (at-LLC) stores; next step reads it with PLAIN CACHED
//    loads. Every rf address is written exactly once, before its only read,
//    and the kernel-launch acquire invalidated all L2s -> a cached read is
//    always a cold miss onto LLC-fresh data. NO cache maintenance, NO sc0sc1
//    reads: L2 dedups the 20x cross-block re-read within an XCD (XCD-area
//    swizzle), cutting the ~5.8 TB/s MALL read demand ~20x (R9 falsified the
//    latency model; throughput is the load-phase constraint).
//  ROT=0: exact R8 scheme (sc0sc1 reads, 2-buffer ping-pong) as fallback.
// Shared (R8-proven): hierarchical 8x20->master->replicated-gen relaxed
// barrier, fast retanh, tail reorder, A pinned in VGPRs, x in regs, no
// whole-cache ops in the loop (R1/R6 catastrophes).
// ---------------------------------------------------------------------------
template <int ROT>
__global__ __launch_bounds__(512, ROT ? 1 : 2) void rnn_persist(
    const _Float16* __restrict__ Af,
    const float* __restrict__ inputs,
    _Float16* __restrict__ rfbase,
    const float* __restrict__ brec,
    float* __restrict__ rates,
    unsigned* bar, int T)
{
  __shared__ float red[8][1056];     // 8 wave-partials, 16 x 66-padded
  __shared__ float rrt[16][68];      // rates staging (padded)
  __shared__ float bb[16];

  const int bid = blockIdx.x;
  int hg_;
  if (ROT) {
    // XCD-area swizzle (round-robin bid&7 = XCD, m09): XCD x hosts area x>>1.
    int x = bid & 7, aa = x >> 1, idx = (x & 1) * 20 + (bid >> 3);
    hg_ = (idx < 32) ? (aa * 32 + idx) : (128 + aa * 8 + (idx - 32));
  } else {
    hg_ = bid;
  }
  const int hg  = hg_;
  const int tid = threadIdx.x;
  const int w   = tid >> 6, L = tid & 63;
  const int h0  = hg * 16;
  const int a   = (hg < 128) ? (hg >> 5) : ((hg - 128) >> 3);
  const int nE  = (a == 0 || a == 3) ? 8 : 12;
  const int SK  = (nE + 1 + (a == 0 ? 1 : 0)) * 4;   // 40 / 52 / 52 / 36
  const int ktE0 = (a == 0 ? 0 : a - 1) * 16;
  const int ktI0 = 64 + a * 4;

  unsigned* bsub = bar + (hg & 7) * 64;        // 8 sub-counters, 20 blocks ea
                                               // (swizzled map also gives 20)
  unsigned* bmas = bar + 8 * 64;               // master (+1 per sub-group)
  unsigned* bgen = bar + (9 + (hg & 7)) * 64;  // replicated release flag

  if (tid < 16) bb[tid] = brec[h0 + tid];

  // ---- one-time A preload + pin in VGPRs ----
  half8 ah[MAXI], al[MAXI];
  int   boff[MAXI];
  bool  act[MAXI], isin[MAXI];
  const _Float16* Abase = Af + (size_t)hg * MAXC * 4096;
  #pragma unroll
  for (int i = 0; i < MAXI; ++i) {
    half8 zz = {0,0,0,0,0,0,0,0};
    ah[i] = zz; al[i] = zz;
    int ks = w + i * 8;
    act[i]  = ks < SK;
    isin[i] = false;
    boff[i] = 0;
    if (act[i]) {
      int c = ks >> 2, kq = ks & 3;
      const _Float16* Ap = Abase + (size_t)c * 4096 + (size_t)(kq * 2) * 512 + (size_t)L * 8;
      ah[i] = *(const half8*)Ap;
      al[i] = *(const half8*)(Ap + 512);
      if (c <= nE) {           // recurrent chunk: rf offset (half units)
        int kt = (c < nE) ? (ktE0 + c * 4 + kq) : (ktI0 + kq);
        boff[i] = kt * 2048 + L * 8;
      } else {                 // input chunk (area 0): inputs offset base
        isin[i] = true;
        boff[i] = kq * 32 + (L >> 4) * 8;
      }
    }
  }
  #pragma unroll
  for (int i = 0; i < MAXI; ++i)
    asm volatile("" : "+v"(ah[i]), "+v"(al[i]));

  float xv[2] = {0.f, 0.f};    // x state: 2 elems/thread, lives in regs

  __syncthreads();             // bb ready

  for (int t = 0; t < T; ++t) {
    const _Float16* __restrict__ rs;
    _Float16* __restrict__ rd;
    if (ROT) {
      rs = rfbase + (size_t)t * RFSTRIDE;        // slot t (fresh addresses)
      rd = rfbase + (size_t)(t + 1) * RFSTRIDE;  // slot t+1 (never touched)
    } else {
      rs = (t & 1) ? (rfbase + RFSTRIDE) : rfbase;
      rd = (t & 1) ? rfbase : (rfbase + RFSTRIDE);
    }

    floatx4 ac0 = {0.f,0.f,0.f,0.f}, ac1 = {0.f,0.f,0.f,0.f};
    floatx4 ac2 = {0.f,0.f,0.f,0.f}, ac3 = {0.f,0.f,0.f,0.f};

    if (ROT) {
      // plain cached loads: L2-dedup'd across the XCD's blocks; compiler
      // software-pipelines all 7 chunk loads.
      #pragma unroll
      for (int i = 0; i < MAXI; ++i) {
        if (!act[i]) continue;                   // wave-uniform
        half8 b0, b1, b2, b3;
        if (isin[i]) {
          const float* ip = inputs + (size_t)t * (Bn * INW) + boff[i];
          int nb = L & 15;
          #pragma unroll
          for (int j = 0; j < 8; ++j) b0[j] = (_Float16)ip[(nb +  0) * INW + j];
          #pragma unroll
          for (int j = 0; j < 8; ++j) b1[j] = (_Float16)ip[(nb + 16) * INW + j];
          #pragma unroll
          for (int j = 0; j < 8; ++j) b2[j] = (_Float16)ip[(nb + 32) * INW + j];
          #pragma unroll
          for (int j = 0; j < 8; ++j) b3[j] = (_Float16)ip[(nb + 48) * INW + j];
        } else {
          const _Float16* Bp = rs + boff[i];
          b0 = *(const half8*)(Bp);
          b1 = *(const half8*)(Bp + 512);
          b2 = *(const half8*)(Bp + 1024);
          b3 = *(const half8*)(Bp + 1536);
        }
        MFMA8(i, b0, b1, b2, b3);
      }
    } else {
      PAIR(0, 1);
      PAIR(2, 3);
      PAIR(4, 5);
      if (act[6]) { if (!isin[6]) RECPATH1(6); else INPATH(6); }
    }

    // dump split-k partials to LDS
    #pragma unroll
    for (int p = 0; p < 4; ++p) {
      int m = (L >> 4) * 4 + p;
      float* rw = &red[w][m * 66 + (L & 15)];
      rw[ 0] = ac0[p];
      rw[16] = ac1[p];
      rw[32] = ac2[p];
      rw[48] = ac3[p];
    }
    __syncthreads();

    // reduce 8 partials + bias + leaky-integrate + fast retanh (R7/R8-proven)
    #pragma unroll
    for (int e = 0; e < 2; ++e) {
      int elem = tid + e * 512;
      int m = elem >> 6, n = elem & 63;
      float s = 0.f;
      #pragma unroll
      for (int j = 0; j < 8; ++j) s += red[j][m * 66 + n];
      float x = 0.8f * xv[e] + 0.2f * (s + bb[m]);   // ALPHA_X = 0.2
      xv[e] = x;
      float xr = fmaxf(x, 0.f);
      float e2 = __builtin_amdgcn_exp2f(xr * 2.885390081777926814f);
      rrt[m][n] = 1.0f - 2.0f * __builtin_amdgcn_rcpf(e2 + 1.0f);
    }
    __syncthreads();

    // tid<128: emit next-step r B-fragments via at-LLC (sc0sc1) stores;
    // vmcnt(0) inside the asm -> data at the LLC before barrier arrival.
    if (tid < 128) {
      int bt = tid >> 5, Lq = tid & 31;
      int Lp = (hg & 1) * 32 + Lq;
      half8 vv;
      #pragma unroll
      for (int j = 0; j < 8; ++j)
        vv[j] = (_Float16)rrt[(Lq >> 4) * 8 + j][bt * 16 + (Lq & 15)];
      _Float16* dst = rd + (size_t)((hg >> 1) * 4 + bt) * 512 + (size_t)Lp * 8;
      asm volatile("global_store_dwordx4 %0, %1, off sc0 sc1\n\t"
                   "s_waitcnt vmcnt(0)"
                   :: "v"(dst), "v"(vv) : "memory");
    }
    __syncthreads();   // all waves' rf stores complete (asm-internal vmcnt 0)

    // ---- arrive (hierarchical, R4/R8-proven), BEFORE the rates store ----
    unsigned g = (unsigned)(t + 1);
    if (t + 1 < T && tid == 0) {
      unsigned s = __hip_atomic_fetch_add(bsub, 1u, __ATOMIC_RELAXED,
                                          __HIP_MEMORY_SCOPE_AGENT);
      if (s == g * 20u - 1u) {
        unsigned m2 = __hip_atomic_fetch_add(bmas, 1u, __ATOMIC_RELAXED,
                                             __HIP_MEMORY_SCOPE_AGENT);
        if (m2 == g * 8u - 1u) {
          #pragma unroll
          for (int x = 0; x < 8; ++x)
            __hip_atomic_store(bar + (9 + x) * 64, g, __ATOMIC_RELAXED,
                               __HIP_MEMORY_SCOPE_AGENT);
        }
      }
    }

    // rates store overlaps the poll below (HBM drain off the critical path)
    if (tid >= 256) {
      int tt = tid - 256;
      int b = tt >> 2, hq = tt & 3;
      floatx4 o;
      o.x = rrt[hq * 4 + 0][b];
      o.y = rrt[hq * 4 + 1][b];
      o.z = rrt[hq * 4 + 2][b];
      o.w = rrt[hq * 4 + 3][b];
      __builtin_nontemporal_store(o,
          (floatx4*)(rates + (size_t)t * (Bn * Hn) + (size_t)b * Hn + h0 + hq * 4));
    }

    if (t + 1 < T) {
      if (tid == 0) {
        while (__hip_atomic_load(bgen, __ATOMIC_RELAXED,
                                 __HIP_MEMORY_SCOPE_AGENT) < g)
          __builtin_amdgcn_s_sleep(2);
      }
      __syncthreads();   // block released
    }
  }
}

// ---------------------------------------------------------------------------
extern "C" void kernel_launch(void* const* d_in, const int* in_sizes, int n_in,
                              void* d_out, int out_size, void* d_ws, size_t ws_size,
                              hipStream_t stream) {
  const float* inputs = (const float*)d_in[0];   // [T, 64, 128]
  const float* Wrec   = (const float*)d_in[1];   // [2560, 2560]
  const float* brec   = (const float*)d_in[2];   // [2560]
  const float* Win    = (const float*)d_in[3];   // [2560, 128]
  int T = in_sizes[0] / (Bn * INW);              // 500

  const size_t afBytes  = (size_t)HGn * MAXC * 4096 * 2;      // 17.0 MB
  const size_t slotB    = (size_t)RFSTRIDE * 2;               // 320 KB
  const size_t rotBytes = (size_t)(T + 1) * slotB;            // ~160.3 MB
  const size_t barBytes = 8192;

  char* base = (char*)d_ws;
  _Float16* Af = (_Float16*)base;
  _Float16* rf = (_Float16*)(base + afBytes);

  const bool rot = ws_size >= afBytes + rotBytes + barBytes + (1u << 20);
  const size_t rfBytes = rot ? rotBytes : 2 * slotB;
  unsigned* bar = (unsigned*)(base + afBytes + rfBytes);

  // slot 0 = r(t=0) = retanh(0) = 0; barrier counters zeroed (ws poisoned
  // each call). Rotation slots 1..T are written before their only read.
  (void)hipMemsetAsync(rf, 0, slotB, stream);
  (void)hipMemsetAsync(bar, 0, barBytes, stream);

  build_apack<<<dim3(HGn, MAXC), 256, 0, stream>>>(Wrec, Win, Af);

  float* rates = (float*)d_out;
  if (rot)
    rnn_persist<1><<<NBLK, 512, 0, stream>>>(Af, inputs, rf, brec, rates, bar, T);
  else
    rnn_persist<0><<<NBLK, 512, 0, stream>>>(Af, inputs, rf, brec, rates, bar, T);
}